// Round 1
// baseline (339.269 us; speedup 1.0000x reference)
//
#include <hip/hip_runtime.h>
#include <math.h>

#define NPIX 4096
#define CIN  512
#define CR   64
#define NB   16

// workspace layout (float offsets)
static const size_t Q_OFF   = 0;                                   // [16][64][4096]
static const size_t W1T_OFF = (size_t)NB * CR * NPIX;              // [512][64]
static const size_t AP_OFF  = W1T_OFF + (size_t)CIN * CR;          // [16][32][64][64]
static const size_t ATT_OFF = AP_OFF + (size_t)NB * 32 * CR * CR;  // [16][64][64]
static const size_t MT_OFF  = ATT_OFF + (size_t)NB * CR * CR;      // [16][64][512]
// total = 6,914,048 floats = 27.7 MB

// K0: w1t[c][o] = w1[o][c]  (contiguous-in-o rows for scalar broadcast loads)
__global__ __launch_bounds__(256) void k0_w1t(const float* __restrict__ w1,
                                              float* __restrict__ w1t) {
    int idx = blockIdx.x * 256 + threadIdx.x;   // 0..32767
    int c = idx >> 6, o = idx & 63;
    w1t[idx] = w1[o * CIN + c];
}

// K1: q[b][o][n] = sum_c w1[o][c] * x[b][c][n] + b1[o]
// grid (16 ntiles, 16 b), block 256. Per-lane x loads (coalesced), weights via
// uniform-address loads -> SGPR broadcast operands of v_fma_f32.
__global__ __launch_bounds__(256) void k1_conv1(const float* __restrict__ x,
                                                const float* __restrict__ w1t,
                                                const float* __restrict__ b1,
                                                float* __restrict__ q) {
    int b = blockIdx.y;
    int n = blockIdx.x * 256 + threadIdx.x;
    const float* xb = x + (size_t)b * CIN * NPIX + n;
    float acc[CR];
#pragma unroll
    for (int o = 0; o < CR; o++) acc[o] = 0.f;
#pragma unroll 4
    for (int c = 0; c < CIN; c++) {
        float xv = xb[(size_t)c * NPIX];
        const float* wr = w1t + c * CR;
#pragma unroll
        for (int o = 0; o < CR; o++) acc[o] += wr[o] * xv;
    }
    float* qb = q + (size_t)b * CR * NPIX + n;
#pragma unroll
    for (int o = 0; o < CR; o++) qb[(size_t)o * NPIX] = acc[o] + b1[o];
}

// K2a: per-(b, n-chunk of 128) partial att: ap[b][ch][c][d] = sum_{n in chunk} q[c][n] q[d][n]
// LDS tile [64][129] (stride 129 -> bank = (c+n)%32, conflict-free), 4x4 register tiles.
__global__ __launch_bounds__(256) void k2a_att_part(const float* __restrict__ q,
                                                    float* __restrict__ ap) {
    __shared__ float qs[CR * 129];
    int b = blockIdx.y, ch = blockIdx.x;
    int t = threadIdx.x;
    const float* qb = q + (size_t)b * CR * NPIX + ch * 128;
#pragma unroll
    for (int i = 0; i < 32; i++) {
        int idx = i * 256 + t;
        int c = idx >> 7, n = idx & 127;
        qs[c * 129 + n] = qb[(size_t)c * NPIX + n];
    }
    __syncthreads();
    int c0 = (t & 15) * 4, d0 = (t >> 4) * 4;
    float acc[4][4];
#pragma unroll
    for (int a = 0; a < 4; a++)
#pragma unroll
        for (int e = 0; e < 4; e++) acc[a][e] = 0.f;
    for (int n = 0; n < 128; n++) {
        float rc[4], rd[4];
#pragma unroll
        for (int a = 0; a < 4; a++) rc[a] = qs[(c0 + a) * 129 + n];
#pragma unroll
        for (int e = 0; e < 4; e++) rd[e] = qs[(d0 + e) * 129 + n];
#pragma unroll
        for (int a = 0; a < 4; a++)
#pragma unroll
            for (int e = 0; e < 4; e++) acc[a][e] += rc[a] * rd[e];
    }
    float* app = ap + ((size_t)(b * 32 + ch) * CR) * CR;
#pragma unroll
    for (int a = 0; a < 4; a++)
#pragma unroll
        for (int e = 0; e < 4; e++)
            app[(c0 + a) * CR + d0 + e] = acc[a][e];
}

// K2b: att[b][c][d] = softmax_d( sum_ch ap[b][ch][c][d] )
// one row = one 64-lane wave; __shfl_xor reductions.
__global__ __launch_bounds__(256) void k2b_softmax(const float* __restrict__ ap,
                                                   float* __restrict__ att) {
    int b = blockIdx.x;
    int t = threadIdx.x;
    int lane = t & 63;   // d
    int wrow = t >> 6;   // starting c (4 waves)
    for (int c = wrow; c < CR; c += 4) {
        float v = 0.f;
        for (int ch = 0; ch < 32; ch++)
            v += ap[(((size_t)(b * 32 + ch) * CR) + c) * CR + lane];
        float m = v;
#pragma unroll
        for (int s = 1; s < 64; s <<= 1) m = fmaxf(m, __shfl_xor(m, s, 64));
        float e = __expf(v - m);
        float ssum = e;
#pragma unroll
        for (int s = 1; s < 64; s <<= 1) ssum += __shfl_xor(ssum, s, 64);
        att[((size_t)b * CR + c) * CR + lane] = e / ssum;
    }
}

// K3: Mt[b][d][c] = sum_k w2[c][k] * att[b][k][d]   (fold conv-out into attention)
// grid (2, 16), block 256: one c per thread, att via uniform scalar loads.
__global__ __launch_bounds__(256) void k3_m(const float* __restrict__ w2,
                                            const float* __restrict__ att,
                                            float* __restrict__ mt) {
    int b = blockIdx.y;
    int c = blockIdx.x * 256 + threadIdx.x;  // 0..511
    const float* ab = att + (size_t)b * CR * CR;
    const float* w2r = w2 + (size_t)c * CR;
    float acc[CR];
#pragma unroll
    for (int o = 0; o < CR; o++) acc[o] = 0.f;
    for (int k = 0; k < CR; k++) {
        float wv = w2r[k];
#pragma unroll
        for (int o = 0; o < CR; o++) acc[o] += wv * ab[k * CR + o];
    }
    float* mtb = mt + (size_t)b * CR * CIN;
#pragma unroll
    for (int o = 0; o < CR; o++) mtb[o * CIN + c] = acc[o];
}

// K4: y[b][c][n] = sum_d Mt[b][d][c] * q[b][d][n] + b2[c] + x[b][c][n]
// grid (16 ntiles, 8 c-chunks, 16 b), block 256; Mt rows via scalar broadcast.
__global__ __launch_bounds__(256) void k4_out(const float* __restrict__ q,
                                              const float* __restrict__ mt,
                                              const float* __restrict__ b2,
                                              const float* __restrict__ x,
                                              float* __restrict__ y) {
    int nt = blockIdx.x, cc = blockIdx.y, b = blockIdx.z;
    int n = nt * 256 + threadIdx.x;
    const float* qb = q + (size_t)b * CR * NPIX + n;
    const float* mtb = mt + (size_t)b * CR * CIN + cc * 64;
    float acc[64];
#pragma unroll
    for (int j = 0; j < 64; j++) acc[j] = 0.f;
#pragma unroll 2
    for (int o = 0; o < CR; o++) {
        float qv = qb[(size_t)o * NPIX];
        const float* mr = mtb + (size_t)o * CIN;
#pragma unroll
        for (int j = 0; j < 64; j++) acc[j] += qv * mr[j];
    }
    size_t base = ((size_t)b * CIN + cc * 64) * NPIX + n;
#pragma unroll
    for (int j = 0; j < 64; j++) {
        y[base + (size_t)j * NPIX] = acc[j] + b2[cc * 64 + j] + x[base + (size_t)j * NPIX];
    }
}

extern "C" void kernel_launch(void* const* d_in, const int* in_sizes, int n_in,
                              void* d_out, int out_size, void* d_ws, size_t ws_size,
                              hipStream_t stream) {
    const float* x  = (const float*)d_in[0];
    const float* w1 = (const float*)d_in[1];
    const float* b1 = (const float*)d_in[2];
    const float* w2 = (const float*)d_in[3];
    const float* b2 = (const float*)d_in[4];
    float* y  = (float*)d_out;
    float* ws = (float*)d_ws;

    float* q   = ws + Q_OFF;
    float* w1t = ws + W1T_OFF;
    float* ap  = ws + AP_OFF;
    float* att = ws + ATT_OFF;
    float* mt  = ws + MT_OFF;

    hipLaunchKernelGGL(k0_w1t,      dim3(128),        dim3(256), 0, stream, w1, w1t);
    hipLaunchKernelGGL(k1_conv1,    dim3(16, 16),     dim3(256), 0, stream, x, w1t, b1, q);
    hipLaunchKernelGGL(k2a_att_part,dim3(32, 16),     dim3(256), 0, stream, q, ap);
    hipLaunchKernelGGL(k2b_softmax, dim3(16),         dim3(256), 0, stream, ap, att);
    hipLaunchKernelGGL(k3_m,        dim3(2, 16),      dim3(256), 0, stream, w2, att, mt);
    hipLaunchKernelGGL(k4_out,      dim3(16, 8, 16),  dim3(256), 0, stream, q, mt, b2, x, y);
}